// Round 3
// baseline (221.075 us; speedup 1.0000x reference)
//
#include <hip/hip_runtime.h>
#include <math.h>

#define EPSV 1e-5f
#define SCALE_W 0.0441941738241592f   /* 1/sqrt(512) */
#define GAIN_R 1.4142135623730951f    /* sqrt(2) */

typedef __attribute__((ext_vector_type(8))) short bf16x8;
typedef __attribute__((ext_vector_type(4))) float f32x4;

static __device__ __forceinline__ unsigned short f2bf(float f) {
  union { float f; unsigned int u; } v; v.f = f;
  unsigned int r = v.u + 0x7FFFu + ((v.u >> 16) & 1u);   // RNE
  return (unsigned short)(r >> 16);
}

#define RED16(v) { v += __shfl_xor(v, 1); v += __shfl_xor(v, 2); v += __shfl_xor(v, 4); v += __shfl_xor(v, 8); }

// ---------------- pre-kernel: b = expmap0(bias), y2 = ||b||^2 ----------------
__global__ void bias_expmap_k(const float* __restrict__ bias, float* __restrict__ bexp,
                              float* __restrict__ y2out) {
  __shared__ float part[8];
  int t = threadIdx.x;
  float bv = bias[t];
  float s = bv * bv;
  s += __shfl_xor(s, 1);  s += __shfl_xor(s, 2);  s += __shfl_xor(s, 4);
  s += __shfl_xor(s, 8);  s += __shfl_xor(s, 16); s += __shfl_xor(s, 32);
  if ((t & 63) == 0) part[t >> 6] = s;
  __syncthreads();
  float tot = 0.f;
#pragma unroll
  for (int i = 0; i < 8; ++i) tot += part[i];
  float un = fmaxf(sqrtf(tot), EPSV);
  float th = tanhf(un);
  bexp[t] = th * bv / un;
  if (t == 0) *y2out = th * th;
}

// ---------------- pre-kernel: pack weight -> bf16 B-fragments, SCALE baked ----
// dst chunk index = (ks*32 + colhi)*64 + lgr*16 + l15, 8 ushorts (j) per chunk.
__global__ void pack_weight_k(const float* __restrict__ w, unsigned short* __restrict__ wsB) {
  int e = blockIdx.x * 256 + threadIdx.x;   // 0..262143
  int o = e >> 9;          // output col (row of W)
  int k = e & 511;
  int ks = k >> 5, kk = k & 31;
  int lgr = kk >> 3, j = kk & 7;
  int colhi = o >> 4, l15 = o & 15;
  int dst = ((ks * 32 + colhi) * 64 + lgr * 16 + l15) * 8 + j;
  wsB[dst] = f2bf(w[e] * SCALE_W);
}

// ---------------- main fused kernel ----------------
// BM=32 rows/block, 256 threads (4 waves x 128 cols).
// LDS: A tile [ks=16][row=32][80B] = 40960 B. Epilogue reuses [0,33024) + scalars @36864.
#define RB 80
#define KSB 2560         /* 32*80 */
#define SMEMSZ 40960

__global__ __launch_bounds__(256, 4)
void hyp_main_k(const float* __restrict__ x, const unsigned short* __restrict__ wsB,
                const float* __restrict__ bexp, const float* __restrict__ y2p,
                float* __restrict__ out) {
  extern __shared__ char smem[];
  const int tid  = threadIdx.x;
  const int lane = tid & 63;
  const int wave = tid >> 6;       // 0..3 : column group (128 cols each)
  const int l15  = lane & 15;
  const int lgr  = lane >> 4;      // 0..3
  const long brow = (long)blockIdx.x * 32;

  // ---- A staging: thread t handles row t>>3, 4 floats at col (t&7)*4 + 32*ks ----
  const int arow  = tid >> 3;      // 0..31
  const float* xptr = x + (size_t)(brow + arow) * 512 + (tid & 7) * 4;
  char* awr = smem + arow * RB + (tid & 7) * 8;

  float xss = 0.f;
  {
    f32x4 buf[8];
#pragma unroll
    for (int i = 0; i < 8; ++i) buf[i] = __builtin_nontemporal_load((const f32x4*)(xptr + i * 32));
#pragma unroll
    for (int ks = 0; ks < 16; ++ks) {
      f32x4 v = buf[ks & 7];
      if (ks < 8) buf[ks & 7] = __builtin_nontemporal_load((const f32x4*)(xptr + (ks + 8) * 32));
      xss += v[0] * v[0] + v[1] * v[1] + v[2] * v[2] + v[3] * v[3];
      uint2 pk;
      pk.x = (unsigned int)f2bf(v[0]) | ((unsigned int)f2bf(v[1]) << 16);
      pk.y = (unsigned int)f2bf(v[2]) | ((unsigned int)f2bf(v[3]) << 16);
      *(uint2*)(awr + ks * KSB) = pk;
    }
  }
  __syncthreads();   // A resident for all 16 K-steps; the ONLY pre-epilogue barrier

  // ---- barrier-free K-loop: LDS A frags + L2-resident global B frags ----
  const char* ard = smem + l15 * RB + lgr * 16;                        // + mf*1280 + ks*2560
  const char* brd = (const char*)wsB + ((size_t)(wave * 8) * 64 + lane) * 16;  // + nf*1024 + ks*32768

  f32x4 acc[2][8];
#pragma unroll
  for (int i = 0; i < 2; ++i)
#pragma unroll
    for (int j = 0; j < 8; ++j) acc[i][j] = f32x4{0.f, 0.f, 0.f, 0.f};

#pragma unroll 4
  for (int ks = 0; ks < 16; ++ks) {
    bf16x8 af[2], bfr[8];
#pragma unroll
    for (int mf = 0; mf < 2; ++mf) af[mf] = *(const bf16x8*)(ard + ks * KSB + mf * (16 * RB));
#pragma unroll
    for (int nf = 0; nf < 8; ++nf) bfr[nf] = *(const bf16x8*)(brd + (size_t)ks * 32768 + nf * 1024);
#pragma unroll
    for (int mf = 0; mf < 2; ++mf)
#pragma unroll
      for (int nf = 0; nf < 8; ++nf)
        acc[mf][nf] = __builtin_amdgcn_mfma_f32_16x16x32_bf16(af[mf], bfr[nf], acc[mf][nf], 0, 0, 0);
  }
  __syncthreads();   // A region dead; epilogue may reuse LDS

  // ---------------- fused hyperbolic epilogue ----------------
  float* tds = (float*)smem;                       // [16][516] transpose staging
  float* xn2 = (float*)(smem + 36864);             // [32]
  float* pS2 = (float*)(smem + 36992);             // [32][4]
  float* pSB = (float*)(smem + 37504);             // [32][4]
  float* g12 = (float*)(smem + 38016);             // [32][2]
  float* pN2 = pS2;                                // reuse (barrier-separated)
  float* tml = pSB;                                // reuse

  // row ||x||^2 : reduce 8 staging threads per row
  float xs = xss;
  xs += __shfl_xor(xs, 1); xs += __shfl_xor(xs, 2); xs += __shfl_xor(xs, 4);
  if ((lane & 7) == 0) xn2[wave * 8 + (lane >> 3)] = xs;

  float bv[8];
#pragma unroll
  for (int nf = 0; nf < 8; ++nf) bv[nf] = bexp[wave * 128 + nf * 16 + l15];

  // per-wave partials: S2 = sum mx^2, SB = sum mx*b over this wave's 128 cols
#pragma unroll
  for (int mf = 0; mf < 2; ++mf)
#pragma unroll
    for (int j = 0; j < 4; ++j) {
      float s2 = 0.f, sb = 0.f;
#pragma unroll
      for (int nf = 0; nf < 8; ++nf) {
        float v = acc[mf][nf][j];
        s2 += v * v;
        sb += v * bv[nf];
      }
      RED16(s2); RED16(sb);
      if (l15 == 0) {
        int r = mf * 16 + lgr * 4 + j;
        pS2[r * 4 + wave] = s2;
        pSB[r * 4 + wave] = sb;
      }
    }
  __syncthreads();

  // per-row scalars: mobius_matvec factor, mobius_add coeffs, project
  if (tid < 32) {
    int r = tid;
    float S2 = 0.f, SB = 0.f;
#pragma unroll
    for (int i = 0; i < 4; ++i) { S2 += pS2[r * 4 + i]; SB += pSB[r * 4 + i]; }
    float y2 = *y2p;
    float xn  = fmaxf(sqrtf(xn2[r]), EPSV);
    float mxn = fmaxf(sqrtf(S2), EPSV);
    float f = tanhf((mxn / xn) * atanhf(fminf(xn, 1.f - EPSV))) / mxn;  // mv = f*mx
    float xy = f * SB;
    float x2 = f * f * S2;
    float den = 1.f + 2.f * xy + x2 * y2 + EPSV;
    float g1 = (1.f + 2.f * xy + y2) * f / den;   // coeff on mx
    float g2 = (1.f - x2) / den;                  // coeff on b
    float n1sq = g1 * g1 * S2 + 2.f * g1 * g2 * SB + g2 * g2 * y2;
    float n1 = fmaxf(sqrtf(fmaxf(n1sq, 0.f)), EPSV);
    if (n1 > 0.999f) { float s = 0.999f / n1; g1 *= s; g2 *= s; }   // project()
    g12[r * 2] = g1; g12[r * 2 + 1] = g2;
  }
  __syncthreads();

  // pass 2: v = lrelu(g1*mx + g2*b); accumulate ||v||^2 ; keep v in acc
#pragma unroll
  for (int mf = 0; mf < 2; ++mf)
#pragma unroll
    for (int j = 0; j < 4; ++j) {
      int r = mf * 16 + lgr * 4 + j;
      float g1 = g12[r * 2], g2 = g12[r * 2 + 1];
      float s2 = 0.f;
#pragma unroll
      for (int nf = 0; nf < 8; ++nf) {
        float v = g1 * acc[mf][nf][j] + g2 * bv[nf];
        v = v > 0.f ? v : 0.2f * v;
        acc[mf][nf][j] = v;
        s2 += v * v;
      }
      RED16(s2);
      if (l15 == 0) pN2[r * 4 + wave] = s2;
    }
  __syncthreads();

  // mobius scalar mult factor
  if (tid < 32) {
    int r = tid;
    float s2 = 0.f;
#pragma unroll
    for (int i = 0; i < 4; ++i) s2 += pN2[r * 4 + i];
    float n2 = fmaxf(sqrtf(s2), EPSV);
    tml[r] = tanhf(GAIN_R * atanhf(fminf(n2, 1.f - EPSV))) / n2;
  }

  // ---- store: transpose through LDS; nontemporal contiguous float4 lines ----
#pragma unroll
  for (int mf = 0; mf < 2; ++mf) {
    __syncthreads();   // tml ready / previous read-phase done before overwrite
#pragma unroll
    for (int j = 0; j < 4; ++j) {
      int rl = lgr * 4 + j;
      float tm = tml[mf * 16 + rl];
#pragma unroll
      for (int nf = 0; nf < 8; ++nf)
        tds[rl * 516 + wave * 128 + nf * 16 + l15] = tm * acc[mf][nf][j];
    }
    __syncthreads();
#pragma unroll
    for (int i = 0; i < 8; ++i) {
      int fi = i * 256 + tid;
      int row = fi >> 7, c4 = fi & 127;
      f32x4 v = *(const f32x4*)(tds + row * 516 + c4 * 4);
      __builtin_nontemporal_store(v, (f32x4*)(out + (size_t)(brow + mf * 16 + row) * 512 + c4 * 4));
    }
  }
}

extern "C" void kernel_launch(void* const* d_in, const int* in_sizes, int n_in,
                              void* d_out, int out_size, void* d_ws, size_t ws_size,
                              hipStream_t stream) {
  const float* x    = (const float*)d_in[0];
  const float* w    = (const float*)d_in[1];
  const float* bias = (const float*)d_in[2];
  float* out = (float*)d_out;

  unsigned short* wsB = (unsigned short*)d_ws;                 // 524288 B
  float* bexp = (float*)((char*)d_ws + 524288);                // 2048 B
  float* y2p  = (float*)((char*)d_ws + 524288 + 2048);         // 4 B

  bias_expmap_k<<<dim3(1), dim3(512), 0, stream>>>(bias, bexp, y2p);
  pack_weight_k<<<dim3(1024), dim3(256), 0, stream>>>(w, wsB);

  const int nrows = in_sizes[0] / 512;      // 131072
  hyp_main_k<<<dim3(nrows / 32), dim3(256), SMEMSZ, stream>>>(x, wsB, bexp, y2p, out);
}

// Round 4
// 180.887 us; speedup vs baseline: 1.2222x; 1.2222x over previous
//
#include <hip/hip_runtime.h>
#include <math.h>

#define EPSV 1e-5f
#define SCALE_W 0.0441941738241592f   /* 1/sqrt(512) */
#define GAIN_R 1.4142135623730951f    /* sqrt(2) */

typedef __attribute__((ext_vector_type(8))) short bf16x8;
typedef __attribute__((ext_vector_type(4))) float f32x4;

static __device__ __forceinline__ unsigned short f2bf(float f) {
  union { float f; unsigned int u; } v; v.f = f;
  unsigned int r = v.u + 0x7FFFu + ((v.u >> 16) & 1u);   // RNE
  return (unsigned short)(r >> 16);
}

// raw barrier: orders LDS (lgkmcnt) but does NOT drain vmcnt -> prefetches survive
#define LBAR() do {                                          \
  asm volatile("s_waitcnt lgkmcnt(0)" ::: "memory");         \
  __builtin_amdgcn_sched_barrier(0);                         \
  __builtin_amdgcn_s_barrier();                              \
  __builtin_amdgcn_sched_barrier(0);                         \
  asm volatile("" ::: "memory");                             \
} while (0)

// ---------------- pre-kernel: b = expmap0(bias), y2 = ||b||^2 ----------------
__global__ void bias_expmap_k(const float* __restrict__ bias, float* __restrict__ bexp,
                              float* __restrict__ y2out) {
  __shared__ float part[8];
  int t = threadIdx.x;
  float bv = bias[t];
  float s = bv * bv;
  s += __shfl_xor(s, 1);  s += __shfl_xor(s, 2);  s += __shfl_xor(s, 4);
  s += __shfl_xor(s, 8);  s += __shfl_xor(s, 16); s += __shfl_xor(s, 32);
  if ((t & 63) == 0) part[t >> 6] = s;
  __syncthreads();
  float tot = 0.f;
#pragma unroll
  for (int i = 0; i < 8; ++i) tot += part[i];
  float un = fmaxf(sqrtf(tot), EPSV);
  float th = tanhf(un);
  bexp[t] = th * bv / un;
  if (t == 0) *y2out = th * th;
}

// ---------------- pre-kernel: pack weight -> bf16 fragments, SCALE baked ----
// chunk = (ks*32 + colhi)*64 + lgr*16 + l15, 8 ushorts (j) per chunk.
// Lane l of a wave loading chunk base+l gets W[col=colhi*16+(l&15)][k=ks*32+(l>>4)*8+j].
__global__ void pack_weight_k(const float* __restrict__ w, unsigned short* __restrict__ wsB) {
  int e = blockIdx.x * 256 + threadIdx.x;   // 0..262143
  int o = e >> 9;          // output col (row of W)
  int k = e & 511;
  int ks = k >> 5, kk = k & 31;
  int lgr = kk >> 3, j = kk & 7;
  int colhi = o >> 4, l15 = o & 15;
  int dst = ((ks * 32 + colhi) * 64 + lgr * 16 + l15) * 8 + j;
  wsB[dst] = f2bf(w[e] * SCALE_W);
}

// ---------------- main fused kernel ----------------
// 512 thr (8 waves x 64 cols), BM=32 rows/tile, K split into 2 halves of 8 ks.
// Double-buffered A half-tiles: buf[2] of [ks=8][row=32][80B]; superstep pipeline.
#define RB 80
#define KSROW 2560       /* 32*80 */
#define BUFSZ 20480      /* 8*2560 */
#define SC_OFF 40960
#define SMEMSZ 43392

__global__ __launch_bounds__(512, 4)
void hyp_main_k(const float* __restrict__ x, const unsigned short* __restrict__ wsB,
                const float* __restrict__ bexp, const float* __restrict__ y2p,
                float* __restrict__ out, int tilesPerBlk) {
  extern __shared__ char smem[];
  const int tid  = threadIdx.x;
  const int lane = tid & 63;
  const int wave = tid >> 6;       // 0..7 : w-col group (64 cols each)
  const int l15  = lane & 15;
  const int lgr  = lane >> 4;      // 0..3
  const int srow = tid >> 4;       // stage row 0..31
  const int scol = tid & 15;

  float* xn2 = (float*)(smem + SC_OFF);          // [32] (reused as tml)
  float* pS2 = (float*)(smem + SC_OFF + 128);    // [32][8] (reused as pN2)
  float* pSB = (float*)(smem + SC_OFF + 1152);   // [32][8]
  float* g12 = (float*)(smem + SC_OFF + 2176);   // [32][2]

  // hoisted expmap'd-bias fragment values: bv4[nf][j] = b[wave*64+nf*16+lgr*4+j]
  f32x4 bv4[4];
#pragma unroll
  for (int nf = 0; nf < 4; ++nf) bv4[nf] = *(const f32x4*)(bexp + wave * 64 + nf * 16 + lgr * 4);

  f32x4 acc[2][4];
#pragma unroll
  for (int mf = 0; mf < 2; ++mf)
#pragma unroll
    for (int nf = 0; nf < 4; ++nf) acc[mf][nf] = f32x4{0.f, 0.f, 0.f, 0.f};

  const char* ard0 = smem + l15 * RB + lgr * 16;                              // + mf*1280 + ks*KSROW + buf
  const char* brd  = (const char*)wsB + ((wave * 4) * 64 + lane) * 16;        // + nf*1024 + ksg*32768
  char* awr0 = smem + srow * RB + (scol & 7) * 8;                             // + (2i+(scol>>3))*KSROW + buf

  const long base = (long)blockIdx.x * tilesPerBlk;
  const int nss = 2 * tilesPerBlk;
  float xss = 0.f;
  f32x4 st[4];

  // ---- prologue: stage superstep 0 (tile base, half 0) ----
  {
    const float* p = x + (size_t)(base * 32 + srow) * 512 + scol * 4;
#pragma unroll
    for (int i = 0; i < 4; ++i) st[i] = *(const f32x4*)(p + i * 64);
#pragma unroll
    for (int i = 0; i < 4; ++i) {
      f32x4 v = st[i];
      xss += v[0] * v[0] + v[1] * v[1] + v[2] * v[2] + v[3] * v[3];
      uint2 pk;
      pk.x = (unsigned int)f2bf(v[0]) | ((unsigned int)f2bf(v[1]) << 16);
      pk.y = (unsigned int)f2bf(v[2]) | ((unsigned int)f2bf(v[3]) << 16);
      *(uint2*)(awr0 + (2 * i + (scol >> 3)) * KSROW) = pk;
    }
  }
  LBAR();

  for (int s = 0; s < nss; ++s) {
    const int h = s & 1;
    const long tile = base + (s >> 1);
    const char* bufC = smem + (s & 1) * BUFSZ;

    // ---- issue-early: x-loads for superstep s+1 (stay in flight through K-loop) ----
    if (s + 1 < nss) {
      const float* p = x + (size_t)((base + ((s + 1) >> 1)) * 32 + srow) * 512 +
                       ((s + 1) & 1) * 256 + scol * 4;
#pragma unroll
      for (int i = 0; i < 4; ++i) st[i] = *(const f32x4*)(p + i * 64);
    }

    // ---- K-loop (8 ks): LDS x-frags (B-op) x L2 w-frags (A-op), swapped MFMA ----
#pragma unroll
    for (int ks = 0; ks < 8; ++ks) {
      bf16x8 xf[2], wf[4];
#pragma unroll
      for (int mf = 0; mf < 2; ++mf)
        xf[mf] = *(const bf16x8*)(bufC + ks * KSROW + mf * (16 * RB) + (size_t)(ard0 - smem));
#pragma unroll
      for (int nf = 0; nf < 4; ++nf)
        wf[nf] = *(const bf16x8*)(brd + (size_t)(h * 8 + ks) * 32768 + nf * 1024);
#pragma unroll
      for (int mf = 0; mf < 2; ++mf)
#pragma unroll
        for (int nf = 0; nf < 4; ++nf)
          acc[mf][nf] = __builtin_amdgcn_mfma_f32_16x16x32_bf16(wf[nf], xf[mf], acc[mf][nf], 0, 0, 0);
    }

    // ---- epilogue at end of each tile (h==1), before the next convert/ds_write ----
    if (h == 1) {
      // row ||x||^2: 16 staging threads per row are consecutive lanes
      float xs = xss;
      xs += __shfl_xor(xs, 1); xs += __shfl_xor(xs, 2);
      xs += __shfl_xor(xs, 4); xs += __shfl_xor(xs, 8);
      if (scol == 0) xn2[srow] = xs;
      xss = 0.f;

      // per-wave partials over this wave's 64 w-cols
      float s2[2] = {0.f, 0.f}, sb[2] = {0.f, 0.f};
#pragma unroll
      for (int mf = 0; mf < 2; ++mf)
#pragma unroll
        for (int nf = 0; nf < 4; ++nf)
#pragma unroll
          for (int j = 0; j < 4; ++j) {
            float v = acc[mf][nf][j];
            s2[mf] += v * v;
            sb[mf] += v * bv4[nf][j];
          }
#pragma unroll
      for (int mf = 0; mf < 2; ++mf) {
        s2[mf] += __shfl_xor(s2[mf], 16); s2[mf] += __shfl_xor(s2[mf], 32);
        sb[mf] += __shfl_xor(sb[mf], 16); sb[mf] += __shfl_xor(sb[mf], 32);
      }
      if (lane < 16) {
#pragma unroll
        for (int mf = 0; mf < 2; ++mf) {
          pS2[(mf * 16 + l15) * 8 + wave] = s2[mf];
          pSB[(mf * 16 + l15) * 8 + wave] = sb[mf];
        }
      }
      LBAR();

      if (tid < 32) {
        int r = tid;
        float S2 = 0.f, SB = 0.f;
#pragma unroll
        for (int i = 0; i < 8; ++i) { S2 += pS2[r * 8 + i]; SB += pSB[r * 8 + i]; }
        float y2 = *y2p;
        float xn  = fmaxf(sqrtf(xn2[r]), EPSV);
        float mxn = fmaxf(sqrtf(S2), EPSV);
        float f = tanhf((mxn / xn) * atanhf(fminf(xn, 1.f - EPSV))) / mxn;  // mv = f*mx
        float xy = f * SB;
        float x2 = f * f * S2;
        float den = 1.f + 2.f * xy + x2 * y2 + EPSV;
        float g1 = (1.f + 2.f * xy + y2) * f / den;   // coeff on mx
        float g2 = (1.f - x2) / den;                  // coeff on b
        float n1sq = g1 * g1 * S2 + 2.f * g1 * g2 * SB + g2 * g2 * y2;
        float n1 = fmaxf(sqrtf(fmaxf(n1sq, 0.f)), EPSV);
        if (n1 > 0.999f) { float sc = 0.999f / n1; g1 *= sc; g2 *= sc; }   // project()
        g12[r * 2] = g1; g12[r * 2 + 1] = g2;
      }
      LBAR();

      // pass 2: v = lrelu(g1*mx + g2*b); ||v||^2 partials; v kept in acc
      float n2p[2] = {0.f, 0.f};
#pragma unroll
      for (int mf = 0; mf < 2; ++mf) {
        float g1 = g12[(mf * 16 + l15) * 2], g2 = g12[(mf * 16 + l15) * 2 + 1];
#pragma unroll
        for (int nf = 0; nf < 4; ++nf)
#pragma unroll
          for (int j = 0; j < 4; ++j) {
            float v = g1 * acc[mf][nf][j] + g2 * bv4[nf][j];
            v = v > 0.f ? v : 0.2f * v;
            acc[mf][nf][j] = v;
            n2p[mf] += v * v;
          }
      }
#pragma unroll
      for (int mf = 0; mf < 2; ++mf) {
        n2p[mf] += __shfl_xor(n2p[mf], 16); n2p[mf] += __shfl_xor(n2p[mf], 32);
      }
      if (lane < 16) {
#pragma unroll
        for (int mf = 0; mf < 2; ++mf) pS2[(mf * 16 + l15) * 8 + wave] = n2p[mf];  // pN2
      }
      LBAR();

      if (tid < 32) {
        int r = tid;
        float sn = 0.f;
#pragma unroll
        for (int i = 0; i < 8; ++i) sn += pS2[r * 8 + i];
        float n2 = fmaxf(sqrtf(sn), EPSV);
        xn2[r] = tanhf(GAIN_R * atanhf(fminf(n2, 1.f - EPSV))) / n2;  // tml
      }
      LBAR();

      // store: 4 consecutive floats per lane per (mf,nf) -> f32x4 direct from regs
#pragma unroll
      for (int mf = 0; mf < 2; ++mf) {
        float tm = xn2[mf * 16 + l15];
#pragma unroll
        for (int nf = 0; nf < 4; ++nf) {
          f32x4 o = acc[mf][nf];
          o[0] *= tm; o[1] *= tm; o[2] *= tm; o[3] *= tm;
          *(f32x4*)(out + (size_t)(tile * 32 + mf * 16 + l15) * 512 +
                    wave * 64 + nf * 16 + lgr * 4) = o;
          acc[mf][nf] = f32x4{0.f, 0.f, 0.f, 0.f};
        }
      }
    }

    // ---- write-late: convert staged regs -> LDS buf[(s+1)&1] ----
    if (s + 1 < nss) {
      char* awr = smem + ((s + 1) & 1) * BUFSZ + (size_t)(awr0 - smem);
#pragma unroll
      for (int i = 0; i < 4; ++i) {
        f32x4 v = st[i];
        xss += v[0] * v[0] + v[1] * v[1] + v[2] * v[2] + v[3] * v[3];
        uint2 pk;
        pk.x = (unsigned int)f2bf(v[0]) | ((unsigned int)f2bf(v[1]) << 16);
        pk.y = (unsigned int)f2bf(v[2]) | ((unsigned int)f2bf(v[3]) << 16);
        *(uint2*)(awr + (2 * i + (scol >> 3)) * KSROW) = pk;
      }
    }
    LBAR();
  }
}

extern "C" void kernel_launch(void* const* d_in, const int* in_sizes, int n_in,
                              void* d_out, int out_size, void* d_ws, size_t ws_size,
                              hipStream_t stream) {
  const float* x    = (const float*)d_in[0];
  const float* w    = (const float*)d_in[1];
  const float* bias = (const float*)d_in[2];
  float* out = (float*)d_out;

  unsigned short* wsB = (unsigned short*)d_ws;                 // 524288 B
  float* bexp = (float*)((char*)d_ws + 524288);                // 2048 B
  float* y2p  = (float*)((char*)d_ws + 524288 + 2048);         // 4 B

  bias_expmap_k<<<dim3(1), dim3(512), 0, stream>>>(bias, bexp, y2p);
  pack_weight_k<<<dim3(1024), dim3(256), 0, stream>>>(w, wsB);

  const int nrows  = in_sizes[0] / 512;      // 131072
  const int ntiles = nrows / 32;             // 4096
  const int nblk   = 1024;
  const int tpb    = ntiles / nblk;          // 4
  hyp_main_k<<<dim3(nblk), dim3(512), SMEMSZ, stream>>>(x, wsB, bexp, y2p, out, tpb);
}

// Round 5
// 177.683 us; speedup vs baseline: 1.2442x; 1.0180x over previous
//
#include <hip/hip_runtime.h>
#include <math.h>

#define EPSV 1e-5f
#define SCALE_W 0.0441941738241592f   /* 1/sqrt(512) */
#define GAIN_R 1.4142135623730951f    /* sqrt(2) */

typedef __attribute__((ext_vector_type(8))) short bf16x8;
typedef __attribute__((ext_vector_type(4))) float f32x4;

static __device__ __forceinline__ unsigned short f2bf(float f) {
  union { float f; unsigned int u; } v; v.f = f;
  unsigned int r = v.u + 0x7FFFu + ((v.u >> 16) & 1u);   // RNE
  return (unsigned short)(r >> 16);
}

// raw barrier: orders LDS (lgkmcnt) but does NOT drain vmcnt -> prefetches survive
#define LBAR() do {                                          \
  asm volatile("s_waitcnt lgkmcnt(0)" ::: "memory");         \
  __builtin_amdgcn_sched_barrier(0);                         \
  __builtin_amdgcn_s_barrier();                              \
  __builtin_amdgcn_sched_barrier(0);                         \
  asm volatile("" ::: "memory");                             \
} while (0)

// ---------------- pre-kernel: b = expmap0(bias), y2 = ||b||^2 ----------------
__global__ void bias_expmap_k(const float* __restrict__ bias, float* __restrict__ bexp,
                              float* __restrict__ y2out) {
  __shared__ float part[8];
  int t = threadIdx.x;
  float bv = bias[t];
  float s = bv * bv;
  s += __shfl_xor(s, 1);  s += __shfl_xor(s, 2);  s += __shfl_xor(s, 4);
  s += __shfl_xor(s, 8);  s += __shfl_xor(s, 16); s += __shfl_xor(s, 32);
  if ((t & 63) == 0) part[t >> 6] = s;
  __syncthreads();
  float tot = 0.f;
#pragma unroll
  for (int i = 0; i < 8; ++i) tot += part[i];
  float un = fmaxf(sqrtf(tot), EPSV);
  float th = tanhf(un);
  bexp[t] = th * bv / un;
  if (t == 0) *y2out = th * th;
}

// ---------------- pre-kernel: pack weight -> bf16 fragments, SCALE baked ----
// chunk = (ks*32 + colhi)*64 + lgr*16 + l15, 8 ushorts (j) per chunk.
// Lane l of a wave loading chunk base+l gets W[col=colhi*16+(l&15)][k=ks*32+(l>>4)*8+j].
__global__ void pack_weight_k(const float* __restrict__ w, unsigned short* __restrict__ wsB) {
  int e = blockIdx.x * 256 + threadIdx.x;   // 0..262143
  int o = e >> 9;          // output col (row of W)
  int k = e & 511;
  int ks = k >> 5, kk = k & 31;
  int lgr = kk >> 3, j = kk & 7;
  int colhi = o >> 4, l15 = o & 15;
  int dst = ((ks * 32 + colhi) * 64 + lgr * 16 + l15) * 8 + j;
  wsB[dst] = f2bf(w[e] * SCALE_W);
}

// ---------------- main fused kernel ----------------
// 256 thr (4 waves), BM=64 rows/tile, wave tile 64x128 (mf=4, nf=8, acc 128).
// K streamed in quarters (4 ks = 128 k), double-buffered A: buf[2] of [4ks][64r][80B].
#define RB 80
#define KSROW 5120       /* 64*80 : one ks slice */
#define BUFSZ 20480      /* 4 ks slices */
#define SC_OFF 40960
#define SMEMSZ 43776

__global__ __launch_bounds__(256, 2)
void hyp_main_k(const float* __restrict__ x, const unsigned short* __restrict__ wsB,
                const float* __restrict__ bexp, const float* __restrict__ y2p,
                float* __restrict__ out, int tilesPerBlk) {
  extern __shared__ char smem[];
  const int tid  = threadIdx.x;
  const int lane = tid & 63;
  const int wave = tid >> 6;       // 0..3 : w-col group (128 cols each)
  const int l15  = lane & 15;
  const int lgr  = lane >> 4;      // 0..3
  const int srow = tid >> 2;       // stage row 0..63
  const int sq   = tid & 3;        // which ks-slice within superstep

  float* xn2 = (float*)(smem + SC_OFF);          // [64] (reused as tml)
  float* pS2 = (float*)(smem + SC_OFF + 256);    // [64][4] (reused as pN2)
  float* pSB = (float*)(smem + SC_OFF + 1280);   // [64][4]
  float* g12 = (float*)(smem + SC_OFF + 2304);   // [64][2]

  const char* ard0 = smem + l15 * RB + lgr * 16;                         // + mf*1280 + ksl*KSROW + buf
  const char* brd  = (const char*)wsB + ((size_t)(wave * 8) * 64 + lane) * 16;  // + nf*1024 + gks*32768
  char* awr0 = smem + sq * KSROW + srow * RB;                            // + i*8 + buf

  f32x4 acc[4][8];
#pragma unroll
  for (int mf = 0; mf < 4; ++mf)
#pragma unroll
    for (int nf = 0; nf < 8; ++nf) acc[mf][nf] = f32x4{0.f, 0.f, 0.f, 0.f};

  const long base = (long)blockIdx.x * tilesPerBlk;
  const int nss = 4 * tilesPerBlk;
  float xss = 0.f;
  f32x4 st[8];

  // ---- prologue: stage superstep 0 (tile base, k 0..127) ----
  {
    const float* p = x + (size_t)(base * 64 + srow) * 512 + sq * 32;
#pragma unroll
    for (int i = 0; i < 8; ++i) st[i] = *(const f32x4*)(p + i * 4);
#pragma unroll
    for (int i = 0; i < 8; ++i) {
      f32x4 v = st[i];
      xss += v[0] * v[0] + v[1] * v[1] + v[2] * v[2] + v[3] * v[3];
      uint2 pk;
      pk.x = (unsigned int)f2bf(v[0]) | ((unsigned int)f2bf(v[1]) << 16);
      pk.y = (unsigned int)f2bf(v[2]) | ((unsigned int)f2bf(v[3]) << 16);
      *(uint2*)(awr0 + i * 8) = pk;
    }
  }
  LBAR();

  for (int s = 0; s < nss; ++s) {
    const int q = s & 3;               // quarter within tile
    const int buf = s & 1;

    // ---- issue-early: x-loads for superstep s+1 (in flight through K-loop) ----
    if (s + 1 < nss) {
      const int sp = s + 1;
      const float* p = x + (size_t)((base + (sp >> 2)) * 64 + srow) * 512 + (sp & 3) * 128 + sq * 32;
#pragma unroll
      for (int i = 0; i < 8; ++i) st[i] = *(const f32x4*)(p + i * 4);
    }

    // ---- K-loop (4 ks): LDS x-frags (B-op) x L2 w-frags (A-op), swapped MFMA ----
#pragma unroll
    for (int ksl = 0; ksl < 4; ++ksl) {
      const int gks = q * 4 + ksl;
      bf16x8 xf[4], wf[8];
#pragma unroll
      for (int mf = 0; mf < 4; ++mf)
        xf[mf] = *(const bf16x8*)(ard0 + buf * BUFSZ + ksl * KSROW + mf * 1280);
#pragma unroll
      for (int nf = 0; nf < 8; ++nf)
        wf[nf] = *(const bf16x8*)(brd + (size_t)gks * 32768 + nf * 1024);
#pragma unroll
      for (int mf = 0; mf < 4; ++mf)
#pragma unroll
        for (int nf = 0; nf < 8; ++nf)
          acc[mf][nf] = __builtin_amdgcn_mfma_f32_16x16x32_bf16(wf[nf], xf[mf], acc[mf][nf], 0, 0, 0);
    }

    // ---- epilogue at end of each tile ----
    if (q == 3) {
      const long tile = base + (s >> 2);

      // row ||x||^2: 4 staging threads per row are consecutive lanes
      float xs = xss;
      xs += __shfl_xor(xs, 1); xs += __shfl_xor(xs, 2);
      if (sq == 0) xn2[srow] = xs;
      xss = 0.f;

      // bias fragment values (L1-hot, transient)
      f32x4 bvv[8];
#pragma unroll
      for (int nf = 0; nf < 8; ++nf)
        bvv[nf] = *(const f32x4*)(bexp + wave * 128 + nf * 16 + lgr * 4);

      // per-wave partials over this wave's 128 w-cols
      float s2[4], sb[4];
#pragma unroll
      for (int mf = 0; mf < 4; ++mf) {
        s2[mf] = 0.f; sb[mf] = 0.f;
#pragma unroll
        for (int nf = 0; nf < 8; ++nf)
#pragma unroll
          for (int j = 0; j < 4; ++j) {
            float v = acc[mf][nf][j];
            s2[mf] += v * v;
            sb[mf] += v * bvv[nf][j];
          }
        s2[mf] += __shfl_xor(s2[mf], 16); s2[mf] += __shfl_xor(s2[mf], 32);
        sb[mf] += __shfl_xor(sb[mf], 16); sb[mf] += __shfl_xor(sb[mf], 32);
      }
      if (lane < 16) {
#pragma unroll
        for (int mf = 0; mf < 4; ++mf) {
          pS2[(mf * 16 + l15) * 4 + wave] = s2[mf];
          pSB[(mf * 16 + l15) * 4 + wave] = sb[mf];
        }
      }
      LBAR();

      if (tid < 64) {
        int r = tid;
        float S2 = 0.f, SB = 0.f;
#pragma unroll
        for (int i = 0; i < 4; ++i) { S2 += pS2[r * 4 + i]; SB += pSB[r * 4 + i]; }
        float y2 = *y2p;
        float xn  = fmaxf(sqrtf(xn2[r]), EPSV);
        float mxn = fmaxf(sqrtf(S2), EPSV);
        float f = tanhf((mxn / xn) * atanhf(fminf(xn, 1.f - EPSV))) / mxn;  // mv = f*mx
        float xy = f * SB;
        float x2 = f * f * S2;
        float den = 1.f + 2.f * xy + x2 * y2 + EPSV;
        float g1 = (1.f + 2.f * xy + y2) * f / den;   // coeff on mx
        float g2 = (1.f - x2) / den;                  // coeff on b
        float n1sq = g1 * g1 * S2 + 2.f * g1 * g2 * SB + g2 * g2 * y2;
        float n1 = fmaxf(sqrtf(fmaxf(n1sq, 0.f)), EPSV);
        if (n1 > 0.999f) { float sc = 0.999f / n1; g1 *= sc; g2 *= sc; }   // project()
        g12[r * 2] = g1; g12[r * 2 + 1] = g2;
      }
      LBAR();

      // pass 2: v = lrelu(g1*mx + g2*b); ||v||^2 partials; v kept in acc
      float n2p[4];
#pragma unroll
      for (int mf = 0; mf < 4; ++mf) {
        float g1 = g12[(mf * 16 + l15) * 2], g2 = g12[(mf * 16 + l15) * 2 + 1];
        n2p[mf] = 0.f;
#pragma unroll
        for (int nf = 0; nf < 8; ++nf)
#pragma unroll
          for (int j = 0; j < 4; ++j) {
            float v = g1 * acc[mf][nf][j] + g2 * bvv[nf][j];
            v = v > 0.f ? v : 0.2f * v;
            acc[mf][nf][j] = v;
            n2p[mf] += v * v;
          }
        n2p[mf] += __shfl_xor(n2p[mf], 16); n2p[mf] += __shfl_xor(n2p[mf], 32);
      }
      if (lane < 16) {
#pragma unroll
        for (int mf = 0; mf < 4; ++mf) pS2[(mf * 16 + l15) * 4 + wave] = n2p[mf];  // pN2
      }
      LBAR();

      if (tid < 64) {
        int r = tid;
        float sn = 0.f;
#pragma unroll
        for (int i = 0; i < 4; ++i) sn += pS2[r * 4 + i];
        float n2 = fmaxf(sqrtf(sn), EPSV);
        xn2[r] = tanhf(GAIN_R * atanhf(fminf(n2, 1.f - EPSV))) / n2;  // tml
      }
      LBAR();

      // store: 4 consecutive floats per lane per (mf,nf) -> f32x4 direct from regs
#pragma unroll
      for (int mf = 0; mf < 4; ++mf) {
        float tm = xn2[mf * 16 + l15];
#pragma unroll
        for (int nf = 0; nf < 8; ++nf) {
          f32x4 o = acc[mf][nf];
          o[0] *= tm; o[1] *= tm; o[2] *= tm; o[3] *= tm;
          *(f32x4*)(out + (size_t)(tile * 64 + mf * 16 + l15) * 512 +
                    wave * 128 + nf * 16 + lgr * 4) = o;
          acc[mf][nf] = f32x4{0.f, 0.f, 0.f, 0.f};
        }
      }
    }

    // ---- write-late: convert staged regs -> LDS buf[(s+1)&1] ----
    if (s + 1 < nss) {
      char* awr = awr0 + ((s + 1) & 1) * BUFSZ;
#pragma unroll
      for (int i = 0; i < 8; ++i) {
        f32x4 v = st[i];
        xss += v[0] * v[0] + v[1] * v[1] + v[2] * v[2] + v[3] * v[3];
        uint2 pk;
        pk.x = (unsigned int)f2bf(v[0]) | ((unsigned int)f2bf(v[1]) << 16);
        pk.y = (unsigned int)f2bf(v[2]) | ((unsigned int)f2bf(v[3]) << 16);
        *(uint2*)(awr + i * 8) = pk;
      }
    }
    LBAR();
  }
}

extern "C" void kernel_launch(void* const* d_in, const int* in_sizes, int n_in,
                              void* d_out, int out_size, void* d_ws, size_t ws_size,
                              hipStream_t stream) {
  const float* x    = (const float*)d_in[0];
  const float* w    = (const float*)d_in[1];
  const float* bias = (const float*)d_in[2];
  float* out = (float*)d_out;

  unsigned short* wsB = (unsigned short*)d_ws;                 // 524288 B
  float* bexp = (float*)((char*)d_ws + 524288);                // 2048 B
  float* y2p  = (float*)((char*)d_ws + 524288 + 2048);         // 4 B

  bias_expmap_k<<<dim3(1), dim3(512), 0, stream>>>(bias, bexp, y2p);
  pack_weight_k<<<dim3(1024), dim3(256), 0, stream>>>(w, wsB);

  const int nrows  = in_sizes[0] / 512;      // 131072
  const int ntiles = nrows / 64;             // 2048
  const int nblk   = 512;                    // exactly 2 blocks/CU
  const int tpb    = ntiles / nblk;          // 4
  hyp_main_k<<<dim3(nblk), dim3(256), SMEMSZ, stream>>>(x, wsB, bexp, y2p, out, tpb);
}